// Round 15
// baseline (5450.451 us; speedup 1.0000x reference)
//
#include <hip/hip_runtime.h>

#define BB 32
#define NN 16384
#define CC 64
#define NC 4096
#define T  512             // 8 waves; block runs at 2 waves/SIMD on its CU
#define SLOTS (NN / T)     // 32 points per thread

// ---------------------------------------------------------------------------
// FPS, one block per batch (R10: cross-block sync ~4.6us/iter via L3 = dead).
// Distance chain B1 = fma(dz,dz, fma(dx,dx, dy*dy)) — bitwise-verified (R6).
// R15 vs R14: __launch_bounds__(T, 1)  [was (T, 2)].
//   waves-per-eu lower bound 1 -> 512-reg unified budget per wave. R7/R11/
//   R12/R14 all showed the backend homing the 128-float state in AGPRs
//   (VGPR_Count 48/84 with ~160 accvgpr moves/iter dominating the loop) at
//   every budget <=256; with no pressure at 512 the allocator should keep
//   arrays in arch VGPRs. Occupancy is unchanged (8-wave block = 2/SIMD).
// Also: 4 independent running-max accumulators (break the 32-deep dependent
// fmaxf chain, ~128 -> ~40 cyc latency).
// Wave max via DPP (row_shr 1/2/4/8 + row_bcast 15/31), cross-wave combine
// via one LDS atomicMax on float bits (dist>=0 => bit order == float order).
// Argmax ties: achievers rescan descending + atomicMin (= numpy first-
// occurrence argmax; verified R7-R14). Centroid reload from compact 12B-row
// d_ws buffer (L2-resident; R12: FETCH 38.7->3.1MB for the reload stream).
// Sentinel rotation depth 4, reset slot (it+2)&3 (>=2 barriers from uses).
// ---------------------------------------------------------------------------

template <int CTRL>
__device__ __forceinline__ float dpp_max(float x) {
    const int yi = __builtin_amdgcn_update_dpp(0, __float_as_int(x),
                                               CTRL, 0xf, 0xf, true);
    return fmaxf(x, __int_as_float(yi));
}

__device__ __forceinline__ float wave_max_dpp(float x) {
    x = dpp_max<0x111>(x);   // row_shr:1
    x = dpp_max<0x112>(x);   // row_shr:2
    x = dpp_max<0x114>(x);   // row_shr:4
    x = dpp_max<0x118>(x);   // row_shr:8
    x = dpp_max<0x142>(x);   // row_bcast:15
    x = dpp_max<0x143>(x);   // row_bcast:31
    return x;                // valid in lane 63
}

__global__ __launch_bounds__(T, 1) void fps_kernel(const float* __restrict__ in,
                                                   float* __restrict__ out,
                                                   const float* __restrict__ cpts) {
#pragma clang fp contract(off)
    const int b    = blockIdx.x;
    const int t    = threadIdx.x;
    const int lane = t & 63;

    __shared__ unsigned s_gbits4[4];
    __shared__ int      s_far4[4];

    const float* base = in + (size_t)b * NN * CC;
    const float* cb   = cpts + (size_t)b * NN * 3;

    float px[SLOTS], py[SLOTS], pz[SLOTS], dist[SLOTS];
#pragma unroll
    for (int j = 0; j < SLOTS; ++j) {
        const int i = j * T + t;
        const float4 v = *reinterpret_cast<const float4*>(base + (size_t)i * CC);
        px[j] = v.x; py[j] = v.y; pz[j] = v.z;
        dist[j] = 1e10f;
    }
    if (t < 4) { s_far4[t] = 0x7fffffff; s_gbits4[t] = 0u; }

    float cx = base[0], cy = base[1], cz = base[2];   // point 0
    int   far = 0;
    __syncthreads();

    int* idx_out = reinterpret_cast<int*>(out);

    for (int it = 0; it < NC; ++it) {
        if (t == 0) idx_out[((size_t)b * NC + it) * CC] = far;
        if (it == NC - 1) break;

        // ---- dist update (chain B1, bitwise-exact); 4 independent maxes ----
        float a0 = -1.0f, a1 = -1.0f, a2 = -1.0f, a3 = -1.0f;
#pragma unroll
        for (int j = 0; j < SLOTS; j += 4) {
            {
                const float dx = px[j] - cx, dy = py[j] - cy, dz = pz[j] - cz;
                const float d  = fmaf(dz, dz, fmaf(dx, dx, dy * dy));
                const float nd = fminf(dist[j], d);
                dist[j] = nd; a0 = fmaxf(a0, nd);
            }
            {
                const float dx = px[j+1] - cx, dy = py[j+1] - cy, dz = pz[j+1] - cz;
                const float d  = fmaf(dz, dz, fmaf(dx, dx, dy * dy));
                const float nd = fminf(dist[j+1], d);
                dist[j+1] = nd; a1 = fmaxf(a1, nd);
            }
            {
                const float dx = px[j+2] - cx, dy = py[j+2] - cy, dz = pz[j+2] - cz;
                const float d  = fmaf(dz, dz, fmaf(dx, dx, dy * dy));
                const float nd = fminf(dist[j+2], d);
                dist[j+2] = nd; a2 = fmaxf(a2, nd);
            }
            {
                const float dx = px[j+3] - cx, dy = py[j+3] - cy, dz = pz[j+3] - cz;
                const float d  = fmaf(dz, dz, fmaf(dx, dx, dy * dy));
                const float nd = fminf(dist[j+3], d);
                dist[j+3] = nd; a3 = fmaxf(a3, nd);
            }
        }
        const float lv = fmaxf(fmaxf(a0, a1), fmaxf(a2, a3));

        // ---- wave64 max via DPP; lane 63 -> LDS atomicMax on bits ----
        const float wv = wave_max_dpp(lv);
        if (lane == 63)
            atomicMax(&s_gbits4[it & 3], __float_as_uint(wv));

        if (t == 0) {              // reset slot used 2 iters ahead (barrier-safe)
            s_far4[(it + 2) & 3]   = 0x7fffffff;
            s_gbits4[(it + 2) & 3] = 0u;
        }
        __syncthreads();                                  // A

        const float gm = __uint_as_float(s_gbits4[it & 3]);

        // ---- achievers: first local index (descending), atomicMin ----
        if (lv == gm) {
            int myi = 0x7fffffff;
#pragma unroll
            for (int j = SLOTS - 1; j >= 0; --j)
                myi = (dist[j] == gm) ? (j * T + t) : myi;
            atomicMin(&s_far4[it & 3], myi);
        }
        __syncthreads();                                  // B

        far = s_far4[it & 3];

        // ---- centroid reload from compact L2-resident buffer ----
        cx = cb[(size_t)far * 3 + 0];
        cy = cb[(size_t)far * 3 + 1];
        cz = cb[(size_t)far * 3 + 2];
    }
}

// ---------------------------------------------------------------------------
// One-time xyz compaction: in[b][i][0..2] -> cpts[b][i*3+{0,1,2}] (12B rows).
// ---------------------------------------------------------------------------
__global__ __launch_bounds__(256) void compact_kernel(const float* __restrict__ in,
                                                      float* __restrict__ cpts) {
    const int gid = blockIdx.x * blockDim.x + threadIdx.x;   // one point each
    const int b   = gid >> 14;                               // NN == 16384
    const int i   = gid & (NN - 1);
    const float* src = in + ((size_t)b * NN + i) * CC;
    float* dst = cpts + ((size_t)b * NN + i) * 3;
    dst[0] = src[0];
    dst[1] = src[1];
    dst[2] = src[2];
}

// ---------------------------------------------------------------------------
// Fallback (ws too small): centroid reloads hit the strided input directly.
// ---------------------------------------------------------------------------
__global__ __launch_bounds__(T, 1) void fps_fallback(const float* __restrict__ in,
                                                     float* __restrict__ out) {
#pragma clang fp contract(off)
    const int b    = blockIdx.x;
    const int t    = threadIdx.x;
    const int lane = t & 63;

    __shared__ unsigned s_gbits4[4];
    __shared__ int      s_far4[4];

    const float* base = in + (size_t)b * NN * CC;

    float px[SLOTS], py[SLOTS], pz[SLOTS], dist[SLOTS];
#pragma unroll
    for (int j = 0; j < SLOTS; ++j) {
        const int i = j * T + t;
        const float4 v = *reinterpret_cast<const float4*>(base + (size_t)i * CC);
        px[j] = v.x; py[j] = v.y; pz[j] = v.z;
        dist[j] = 1e10f;
    }
    if (t < 4) { s_far4[t] = 0x7fffffff; s_gbits4[t] = 0u; }

    float cx = base[0], cy = base[1], cz = base[2];
    int   far = 0;
    __syncthreads();

    int* idx_out = reinterpret_cast<int*>(out);

    for (int it = 0; it < NC; ++it) {
        if (t == 0) idx_out[((size_t)b * NC + it) * CC] = far;
        if (it == NC - 1) break;

        float lv = -1.0f;
#pragma unroll
        for (int j = 0; j < SLOTS; ++j) {
            const float dx = px[j] - cx;
            const float dy = py[j] - cy;
            const float dz = pz[j] - cz;
            const float d  = fmaf(dz, dz, fmaf(dx, dx, dy * dy));
            const float nd = fminf(dist[j], d);
            dist[j] = nd;
            lv = fmaxf(lv, nd);
        }

        const float wv = wave_max_dpp(lv);
        if (lane == 63)
            atomicMax(&s_gbits4[it & 3], __float_as_uint(wv));

        if (t == 0) {
            s_far4[(it + 2) & 3]   = 0x7fffffff;
            s_gbits4[(it + 2) & 3] = 0u;
        }
        __syncthreads();

        const float gm = __uint_as_float(s_gbits4[it & 3]);

        if (lv == gm) {
            int myi = 0x7fffffff;
#pragma unroll
            for (int j = SLOTS - 1; j >= 0; --j)
                myi = (dist[j] == gm) ? (j * T + t) : myi;
            atomicMin(&s_far4[it & 3], myi);
        }
        __syncthreads();

        far = s_far4[it & 3];
        cx = base[(size_t)far * CC + 0];
        cy = base[(size_t)far * CC + 1];
        cz = base[(size_t)far * CC + 2];
    }
}

// ---------------------------------------------------------------------------
// Gather kernel: one wave64 per output row (64 channels).
// ---------------------------------------------------------------------------
__global__ __launch_bounds__(256) void gather_kernel(const float* __restrict__ in,
                                                     float* out) {
    const int gid  = blockIdx.x * blockDim.x + threadIdx.x;
    const int row  = gid >> 6;     // 0 .. B*NC-1
    const int lane = gid & 63;     // channel
    const int b = row >> 12;       // NC == 4096
    const int idx = reinterpret_cast<const int*>(out)[(size_t)row * CC];
    const float v = in[((size_t)b * NN + idx) * CC + lane];
    out[(size_t)row * CC + lane] = v;
}

extern "C" void kernel_launch(void* const* d_in, const int* in_sizes, int n_in,
                              void* d_out, int out_size, void* d_ws, size_t ws_size,
                              hipStream_t stream) {
    const float* in = (const float*)d_in[0];
    float* out = (float*)d_out;

    const size_t ws_need = (size_t)BB * NN * 3 * sizeof(float);   // 6 MB
    if (ws_size >= ws_need) {
        float* cpts = (float*)d_ws;
        compact_kernel<<<(BB * NN) / 256, 256, 0, stream>>>(in, cpts);
        fps_kernel<<<BB, T, 0, stream>>>(in, out, cpts);
    } else {
        fps_fallback<<<BB, T, 0, stream>>>(in, out);
    }

    const int total = BB * NC * CC;          // 8,388,608
    gather_kernel<<<total / 256, 256, 0, stream>>>(in, out);
}